// Round 1
// baseline (3023.117 us; speedup 1.0000x reference)
//
#include <hip/hip_runtime.h>
#include <math.h>

typedef unsigned short u16;
typedef unsigned int   u32;

#define E_EDGES 100000
#define NNODES  5000
#define INV_SQRT3 0.57735026918962576f
#define INV_AVG   0.05f

__device__ __forceinline__ float us2f(u16 u) {
    union { float f; u32 i; } c; c.i = ((u32)u) << 16; return c.f;
}
__device__ __forceinline__ u16 f2us(float f) {
    union { float f; u32 i; } c; c.f = f;
    u32 x = c.i;
    x += 0x7fffu + ((x >> 16) & 1u);   // round-to-nearest-even bf16
    return (u16)(x >> 16);
}
__device__ __forceinline__ float siluf(float x) { return x / (1.f + expf(-x)); }

// ---------------------------------------------------------------------------
// Generic GEMM: Y(MxN,bf16) = epi( concat(X1,X2)(MxK,bf16) @ W(KxN,f32) )
// tile: 128 rows x 64 cols per block (256 threads), K-chunks of 16 via LDS.
// EPI: 0 = none, 1 = silu, 2 = multiply row by cut[row]
// ---------------------------------------------------------------------------
template <int EPI>
__global__ __launch_bounds__(256) void gemm_k(
    const u16* __restrict__ X1, int ldx1, int K1,
    const u16* __restrict__ X2, int ldx2, int K2,
    const float* __restrict__ W, int ldw,
    u16* __restrict__ Y, int ldy, int M,
    const float* __restrict__ cut)
{
    __shared__ float Xl[16][128];   // [k][row]
    __shared__ float Wl[16][64];    // [k][col]
    const int t  = threadIdx.x;
    const int m0 = blockIdx.x * 128;
    const int n0 = blockIdx.y * 64;
    const int Kt = K1 + K2;
    const int nch = (Kt + 15) >> 4;
    const int cc = t & 7;    // col group: cols cc*8 .. cc*8+7
    const int rr = t >> 3;   // row group: rows rr*4 .. rr*4+3

    float acc[4][8];
#pragma unroll
    for (int i = 0; i < 4; ++i)
#pragma unroll
        for (int j = 0; j < 8; ++j) acc[i][j] = 0.f;

    const int xr = t >> 1;         // staging: row 0..127
    const int xk = (t & 1) * 8;    // staging: k offset 0/8
    const int wk = t >> 4;         // staging: k 0..15
    const int wn = (t & 15) * 4;   // staging: col

    for (int ch = 0; ch < nch; ++ch) {
        const int k0 = ch << 4;
        // ---- stage X chunk (upconvert bf16 -> f32, transposed [k][row]) ----
        {
            float vals[8];
            const int row = m0 + xr;
            const int kb  = k0 + xk;
            if (row < M) {
                if (kb + 8 <= K1) {
                    uint4 q = *(const uint4*)(X1 + (size_t)row * ldx1 + kb);
                    u32 qs[4] = {q.x, q.y, q.z, q.w};
#pragma unroll
                    for (int j = 0; j < 4; ++j) {
                        vals[2*j]   = us2f((u16)(qs[j] & 0xffffu));
                        vals[2*j+1] = us2f((u16)(qs[j] >> 16));
                    }
                } else if (kb >= K1 && kb + 8 <= Kt) {
                    uint4 q = *(const uint4*)(X2 + (size_t)row * ldx2 + (kb - K1));
                    u32 qs[4] = {q.x, q.y, q.z, q.w};
#pragma unroll
                    for (int j = 0; j < 4; ++j) {
                        vals[2*j]   = us2f((u16)(qs[j] & 0xffffu));
                        vals[2*j+1] = us2f((u16)(qs[j] >> 16));
                    }
                } else {
#pragma unroll
                    for (int j = 0; j < 8; ++j) {
                        int k = kb + j;
                        float v = 0.f;
                        if (k < K1)      v = us2f(X1[(size_t)row * ldx1 + k]);
                        else if (k < Kt) v = us2f(X2[(size_t)row * ldx2 + (k - K1)]);
                        vals[j] = v;
                    }
                }
            } else {
#pragma unroll
                for (int j = 0; j < 8; ++j) vals[j] = 0.f;
            }
#pragma unroll
            for (int j = 0; j < 8; ++j) Xl[xk + j][xr] = vals[j];
        }
        // ---- stage W chunk ----
        {
            const int k = k0 + wk;
            float4 v = make_float4(0.f, 0.f, 0.f, 0.f);
            if (k < Kt) v = *(const float4*)(W + (size_t)k * ldw + n0 + wn);
            *(float4*)&Wl[wk][wn] = v;
        }
        __syncthreads();
        // ---- compute ----
#pragma unroll
        for (int k = 0; k < 16; ++k) {
            float xf[4], wf[8];
            *(float4*)xf       = *(const float4*)&Xl[k][rr * 4];
            *(float4*)wf       = *(const float4*)&Wl[k][cc * 8];
            *(float4*)(wf + 4) = *(const float4*)&Wl[k][cc * 8 + 4];
#pragma unroll
            for (int i = 0; i < 4; ++i)
#pragma unroll
                for (int j = 0; j < 8; ++j)
                    acc[i][j] = fmaf(xf[i], wf[j], acc[i][j]);
        }
        __syncthreads();
    }
    // ---- epilogue + store (8 bf16 = one 16B store per row) ----
#pragma unroll
    for (int i = 0; i < 4; ++i) {
        const int row = m0 + rr * 4 + i;
        if (row < M) {
            float scale = 1.f;
            if (EPI == 2) scale = cut[row];
            u32 w0, w1, w2, w3;
            float v[8];
#pragma unroll
            for (int j = 0; j < 8; ++j) {
                float a = acc[i][j];
                if (EPI == 1) a = siluf(a);
                if (EPI == 2) a = a * scale;
                v[j] = a;
            }
            w0 = (u32)f2us(v[0]) | ((u32)f2us(v[1]) << 16);
            w1 = (u32)f2us(v[2]) | ((u32)f2us(v[3]) << 16);
            w2 = (u32)f2us(v[4]) | ((u32)f2us(v[5]) << 16);
            w3 = (u32)f2us(v[6]) | ((u32)f2us(v[7]) << 16);
            uint4 q = make_uint4(w0, w1, w2, w3);
            *(uint4*)(Y + (size_t)row * ldy + n0 + cc * 8) = q;
        }
    }
}

// ---------------------------------------------------------------------------
// prep: gather X0 = [node[center] | node[neigh] | radial | 0pad] (E x 144 bf16)
// and polynomial cutoff per edge.
// ---------------------------------------------------------------------------
__global__ __launch_bounds__(256) void prep_edges_k(
    const float* __restrict__ na, const float* __restrict__ radial,
    const float* __restrict__ lengths, const int* __restrict__ eidx,
    u16* __restrict__ X0, float* __restrict__ cut)
{
    int idx = blockIdx.x * 256 + threadIdx.x;
    if (idx >= E_EDGES * 144) return;
    int e = idx / 144;
    int k = idx - e * 144;
    float v = 0.f;
    if (k < 64)       v = na[(size_t)eidx[e] * 64 + k];
    else if (k < 128) v = na[(size_t)eidx[E_EDGES + e] * 64 + (k - 64)];
    else if (k < 136) v = radial[(size_t)e * 8 + (k - 128)];
    X0[idx] = f2us(v);
    if (k == 136) {
        float x = lengths[e] * 0.2f;           // r / R_MAX
        float x3 = x * x * x;
        float x6 = x3 * x3, x7 = x6 * x, x8 = x7 * x;
        float o = 1.f - 28.f * x6 + 48.f * x7 - 21.f * x8;
        cut[e] = (x < 1.f) ? o : 0.f;
    }
}

// build lin1 weights transposed to GEMM layout: [(i*64+u)][(o*64+v)]
__global__ __launch_bounds__(256) void prep_lin1_k(
    const float* __restrict__ sw, const float* __restrict__ vw,
    float* __restrict__ SWt, float* __restrict__ VWt)
{
    int idx = blockIdx.x * 256 + threadIdx.x;
    if (idx >= 16384) return;
    int v = idx & 63, u = (idx >> 6) & 63, o = (idx >> 12) & 1, i = idx >> 13;
    int dst = (i * 64 + u) * 128 + o * 64 + v;
    SWt[dst] = sw[idx];
    VWt[dst] = vw[idx];
}

// ---------------------------------------------------------------------------
// stage-B elementwise: split w_all0 (E x 320), gated feat fs/fv, env atomics
// ---------------------------------------------------------------------------
__global__ __launch_bounds__(256) void ew0_k(
    const u16* __restrict__ wall, const float* __restrict__ ang,
    const int* __restrict__ eidx,
    u16* __restrict__ fsg, u16* __restrict__ fvg,
    float* __restrict__ ns_raw, float* __restrict__ nv_raw)
{
    int idx = blockIdx.x * 256 + threadIdx.x;
    if (idx >= E_EDGES * 64) return;
    int e = idx >> 6, u = idx & 63;
    const u16* wr = wall + (size_t)e * 320;
    float we0 = us2f(wr[2 * u]),       we1 = us2f(wr[2 * u + 1]);
    float g   = us2f(wr[128 + u]);
    float wf0 = us2f(wr[192 + 2 * u]), wf1 = us2f(wr[193 + 2 * u]);
    float sh0 = ang[e * 4 + 0], sh1 = ang[e * 4 + 1];
    float sh2 = ang[e * 4 + 2], sh3 = ang[e * 4 + 3];
    fsg[idx] = f2us(wf0 * sh0 * g);
    fvg[(size_t)idx * 3 + 0] = f2us(wf1 * sh1 * g);
    fvg[(size_t)idx * 3 + 1] = f2us(wf1 * sh2 * g);
    fvg[(size_t)idx * 3 + 2] = f2us(wf1 * sh3 * g);
    int ce = eidx[e];
    atomicAdd(&ns_raw[ce * 64 + u], we0 * sh0);
    atomicAdd(&nv_raw[ce * 192 + u * 3 + 0], we1 * sh1);
    atomicAdd(&nv_raw[ce * 192 + u * 3 + 1], we1 * sh2);
    atomicAdd(&nv_raw[ce * 192 + u * 3 + 2], we1 * sh3);
}

// per-node: ns_e = (segsum/20) @ L0 ; nv_e[c] = (segsum/20) @ L1
__global__ __launch_bounds__(64) void nodelin_k(
    const float* __restrict__ ns_raw, const float* __restrict__ nv_raw,
    const float* __restrict__ envlin,
    float* __restrict__ ns_e, float* __restrict__ nv_e)
{
    __shared__ float ss[64];
    __shared__ float sv[192];
    int n = blockIdx.x, v = threadIdx.x;
    ss[v]        = ns_raw[n * 64 + v];
    sv[v]        = nv_raw[n * 192 + v];
    sv[64 + v]   = nv_raw[n * 192 + 64 + v];
    sv[128 + v]  = nv_raw[n * 192 + 128 + v];
    __syncthreads();
    const float* L0 = envlin;
    const float* L1 = envlin + 4096;
    float a0 = 0.f, a1 = 0.f, a2 = 0.f, a3 = 0.f;
#pragma unroll 8
    for (int u = 0; u < 64; ++u) {
        float l0 = L0[u * 64 + v], l1 = L1[u * 64 + v];
        a0 = fmaf(ss[u], l0, a0);
        a1 = fmaf(sv[u * 3 + 0], l1, a1);
        a2 = fmaf(sv[u * 3 + 1], l1, a2);
        a3 = fmaf(sv[u * 3 + 2], l1, a3);
    }
    ns_e[n * 64 + v]            = a0 * INV_AVG;
    nv_e[n * 192 + v]           = a1 * INV_AVG;
    nv_e[n * 192 + 64 + v]      = a2 * INV_AVG;
    nv_e[n * 192 + 128 + v]     = a3 * INV_AVG;
}

// tensor product uuu: ts (E x 128 [i*64+u]), tv (rows e*3+c, 128 cols)
__global__ __launch_bounds__(256) void tp0_k(
    const u16* __restrict__ fsg, const u16* __restrict__ fvg,
    const float* __restrict__ ns_e, const float* __restrict__ nv_e,
    const int* __restrict__ eidx, u16* __restrict__ ts, u16* __restrict__ tv)
{
    int idx = blockIdx.x * 256 + threadIdx.x;
    if (idx >= E_EDGES * 64) return;
    int e = idx >> 6, u = idx & 63;
    int ce = eidx[e];
    float f  = us2f(fsg[idx]);
    float b0 = us2f(fvg[(size_t)idx * 3 + 0]);
    float b1 = us2f(fvg[(size_t)idx * 3 + 1]);
    float b2 = us2f(fvg[(size_t)idx * 3 + 2]);
    float ns = ns_e[ce * 64 + u];
    float n0 = nv_e[ce * 192 + u], n1 = nv_e[ce * 192 + 64 + u], n2 = nv_e[ce * 192 + 128 + u];
    ts[(size_t)e * 128 + u]      = f2us(f * ns);
    ts[(size_t)e * 128 + 64 + u] = f2us((b0 * n0 + b1 * n1 + b2 * n2) * INV_SQRT3);
    size_t tb = (size_t)e * 384;
    tv[tb + u]             = f2us(f * n0 * INV_SQRT3);
    tv[tb + 128 + u]       = f2us(f * n1 * INV_SQRT3);
    tv[tb + 256 + u]       = f2us(f * n2 * INV_SQRT3);
    tv[tb + 64 + u]        = f2us(b0 * ns * INV_SQRT3);
    tv[tb + 128 + 64 + u]  = f2us(b1 * ns * INV_SQRT3);
    tv[tb + 256 + 64 + u]  = f2us(b2 * ns * INV_SQRT3);
}

// latents = sqrt(1-a)*latents + sqrt(a)*cut*new_lat (in place)
__global__ __launch_bounds__(256) void blend_k(
    u16* __restrict__ lat, const u16* __restrict__ nl,
    const float* __restrict__ cut, const float* __restrict__ resp)
{
    int idx = blockIdx.x * 256 + threadIdx.x;
    if (idx >= E_EDGES * 256) return;
    int e = idx >> 8;
    float a  = 1.f / (1.f + expf(-resp[1]));
    float c1 = sqrtf(1.f - a);
    float c2 = sqrtf(a) * cut[e];
    lat[idx] = f2us(c1 * us2f(lat[idx]) + c2 * us2f(nl[idx]));
}

// stage-C elementwise: gate fs1/fv1 in place, env atomics from w_all1 (E x 192)
__global__ __launch_bounds__(256) void ew1_k(
    const u16* __restrict__ wall, const float* __restrict__ ang,
    const int* __restrict__ eidx,
    u16* __restrict__ fs1, u16* __restrict__ fv1,
    float* __restrict__ ns_raw, float* __restrict__ nv_raw)
{
    int idx = blockIdx.x * 256 + threadIdx.x;
    if (idx >= E_EDGES * 64) return;
    int e = idx >> 6, u = idx & 63;
    const u16* wr = wall + (size_t)e * 192;
    float we0 = us2f(wr[2 * u]), we1 = us2f(wr[2 * u + 1]);
    float g   = us2f(wr[128 + u]);
    fs1[idx] = f2us(us2f(fs1[idx]) * g);
    size_t fb = (size_t)e * 192;
    fv1[fb + u]       = f2us(us2f(fv1[fb + u]) * g);
    fv1[fb + 64 + u]  = f2us(us2f(fv1[fb + 64 + u]) * g);
    fv1[fb + 128 + u] = f2us(us2f(fv1[fb + 128 + u]) * g);
    float sh0 = ang[e * 4 + 0], sh1 = ang[e * 4 + 1];
    float sh2 = ang[e * 4 + 2], sh3 = ang[e * 4 + 3];
    int ce = eidx[e];
    atomicAdd(&ns_raw[ce * 64 + u], we0 * sh0);
    atomicAdd(&nv_raw[ce * 192 + u * 3 + 0], we1 * sh1);
    atomicAdd(&nv_raw[ce * 192 + u * 3 + 1], we1 * sh2);
    atomicAdd(&nv_raw[ce * 192 + u * 3 + 2], we1 * sh3);
}

__global__ __launch_bounds__(256) void tp1_k(
    const u16* __restrict__ fs1, const u16* __restrict__ fv1,
    const float* __restrict__ ns_e, const float* __restrict__ nv_e,
    const int* __restrict__ eidx, u16* __restrict__ ts, u16* __restrict__ tv)
{
    int idx = blockIdx.x * 256 + threadIdx.x;
    if (idx >= E_EDGES * 64) return;
    int e = idx >> 6, u = idx & 63;
    int ce = eidx[e];
    float f = us2f(fs1[idx]);
    size_t fb = (size_t)e * 192;
    float b0 = us2f(fv1[fb + u]), b1 = us2f(fv1[fb + 64 + u]), b2 = us2f(fv1[fb + 128 + u]);
    float ns = ns_e[ce * 64 + u];
    float n0 = nv_e[ce * 192 + u], n1 = nv_e[ce * 192 + 64 + u], n2 = nv_e[ce * 192 + 128 + u];
    ts[(size_t)e * 128 + u]      = f2us(f * ns);
    ts[(size_t)e * 128 + 64 + u] = f2us((b0 * n0 + b1 * n1 + b2 * n2) * INV_SQRT3);
    size_t tb = (size_t)e * 384;
    tv[tb + u]             = f2us(f * n0 * INV_SQRT3);
    tv[tb + 128 + u]       = f2us(f * n1 * INV_SQRT3);
    tv[tb + 256 + u]       = f2us(f * n2 * INV_SQRT3);
    tv[tb + 64 + u]        = f2us(b0 * ns * INV_SQRT3);
    tv[tb + 128 + 64 + u]  = f2us(b1 * ns * INV_SQRT3);
    tv[tb + 256 + 64 + u]  = f2us(b2 * ns * INV_SQRT3);
}

// final assembly: out[e][0:128] = fs2*fin ; out[e][128+o*192+v*3+c] = fv2[e,c,o*64+v]
__global__ __launch_bounds__(256) void out_k(
    const u16* __restrict__ fs2, const u16* __restrict__ fin,
    const u16* __restrict__ fv2, float* __restrict__ out)
{
    int idx = blockIdx.x * 256 + threadIdx.x;
    if (idx >= E_EDGES * 512) return;
    int e = idx >> 9, j = idx & 511;
    float v;
    if (j < 128) {
        v = us2f(fs2[(size_t)e * 128 + j]) * us2f(fin[(size_t)e * 128 + j]);
    } else {
        int jj = j - 128;
        int o = (jj >= 192) ? 1 : 0;
        int rem = jj - o * 192;
        int vv = rem / 3;
        int c  = rem - vv * 3;
        v = us2f(fv2[(size_t)e * 384 + (size_t)c * 128 + o * 64 + vv]);
    }
    out[idx] = v;
}

// ---------------------------------------------------------------------------
static void launch_gemm(hipStream_t s, int epi,
                        const u16* X1, int ldx1, int K1,
                        const u16* X2, int ldx2, int K2,
                        const float* W, int ldw,
                        u16* Y, int ldy, int M, int N,
                        const float* cut)
{
    dim3 grid((M + 127) / 128, N / 64);
    dim3 block(256);
    if (epi == 0)      gemm_k<0><<<grid, block, 0, s>>>(X1, ldx1, K1, X2, ldx2, K2, W, ldw, Y, ldy, M, cut);
    else if (epi == 1) gemm_k<1><<<grid, block, 0, s>>>(X1, ldx1, K1, X2, ldx2, K2, W, ldw, Y, ldy, M, cut);
    else               gemm_k<2><<<grid, block, 0, s>>>(X1, ldx1, K1, X2, ldx2, K2, W, ldw, Y, ldy, M, cut);
}

extern "C" void kernel_launch(void* const* d_in, const int* in_sizes, int n_in,
                              void* d_out, int out_size, void* d_ws, size_t ws_size,
                              hipStream_t stream)
{
    const float* node_attrs = (const float*)d_in[0];
    const float* radial     = (const float*)d_in[1];
    const float* ang        = (const float*)d_in[2];
    const float* lengths    = (const float*)d_in[3];
    const int*   eidx       = (const int*)d_in[4];
    const float* tb_w0      = (const float*)d_in[5];
    const float* tb_w1      = (const float*)d_in[6];
    const float* tb_w2      = (const float*)d_in[7];
    const float* lat1_w0    = (const float*)d_in[8];
    const float* lat1_w1    = (const float*)d_in[9];
    const float* env0_w     = (const float*)d_in[10];
    const float* env1_w     = (const float*)d_in[11];
    const float* envlin0    = (const float*)d_in[12];
    const float* envlin1    = (const float*)d_in[13];
    const float* lin0_sw    = (const float*)d_in[14];
    const float* lin0_vw    = (const float*)d_in[15];
    const float* lin1_sw    = (const float*)d_in[16];
    const float* lin1_vw    = (const float*)d_in[17];
    const float* fin_w0     = (const float*)d_in[18];
    const float* fin_w1     = (const float*)d_in[19];
    const float* res_p      = (const float*)d_in[20];

    const size_t E = E_EDGES;
    unsigned char* ws = (unsigned char*)d_ws;
    size_t off = 0;
    auto take = [&](size_t n) -> void* {
        void* p = ws + off;
        off += (n + 255) & ~(size_t)255;
        return p;
    };
    u16*  X0   = (u16*)take(E * 144 * 2);
    float* cut = (float*)take(E * 4);
    u16*  hA   = (u16*)take(E * 256 * 2);
    u16*  hB   = (u16*)take(E * 256 * 2);
    u16*  lat  = (u16*)take(E * 256 * 2);
    u16*  wall = (u16*)take(E * 320 * 2);   // reused for w_all1 (E x 192)
    u16*  fsg  = (u16*)take(E * 64 * 2);
    u16*  fvg  = (u16*)take(E * 192 * 2);
    u16*  ts   = (u16*)take(E * 128 * 2);   // reused for ts2
    u16*  tv   = (u16*)take(E * 384 * 2);   // reused for tv2
    u16*  fs1  = (u16*)take(E * 64 * 2);
    u16*  fv1  = (u16*)take(E * 192 * 2);
    u16*  fs2  = (u16*)take(E * 128 * 2);
    u16*  fv2  = (u16*)take(E * 384 * 2);
    float* nodebuf = (float*)take((size_t)NNODES * 256 * 4 * 2); // 2 stages of raw sums
    float* ns_raw  = nodebuf;
    float* nv_raw  = nodebuf + NNODES * 64;
    float* ns2_raw = nodebuf + NNODES * 256;
    float* nv2_raw = nodebuf + NNODES * 256 + NNODES * 64;
    float* ns_e  = (float*)take((size_t)NNODES * 64 * 4);
    float* nv_e  = (float*)take((size_t)NNODES * 192 * 4);
    float* ns2_e = (float*)take((size_t)NNODES * 64 * 4);
    float* nv2_e = (float*)take((size_t)NNODES * 192 * 4);
    float* SWt = (float*)take(128 * 128 * 4);
    float* VWt = (float*)take(128 * 128 * 4);

    // zero the segment-sum accumulators (ws is poisoned before every call)
    hipMemsetAsync(nodebuf, 0, (size_t)NNODES * 256 * 4 * 2, stream);

    prep_lin1_k<<<64, 256, 0, stream>>>(lin1_sw, lin1_vw, SWt, VWt);
    prep_edges_k<<<(E_EDGES * 144) / 256, 256, 0, stream>>>(node_attrs, radial, lengths, eidx, X0, cut);

    // ---- stage A: two-body MLP -> latents ----
    launch_gemm(stream, 1, X0, 144, 136, nullptr, 0, 0, tb_w0, 256, hA, 256, E_EDGES, 256, nullptr);
    launch_gemm(stream, 1, hA, 256, 256, nullptr, 0, 0, tb_w1, 256, hB, 256, E_EDGES, 256, nullptr);
    launch_gemm(stream, 2, hB, 256, 256, nullptr, 0, 0, tb_w2, 256, lat, 256, E_EDGES, 256, cut);

    // ---- stage B ----
    launch_gemm(stream, 0, lat, 256, 256, nullptr, 0, 0, env0_w, 320, wall, 320, E_EDGES, 320, nullptr);
    ew0_k<<<(E_EDGES * 64) / 256, 256, 0, stream>>>(wall, ang, eidx, fsg, fvg, ns_raw, nv_raw);
    nodelin_k<<<NNODES, 64, 0, stream>>>(ns_raw, nv_raw, envlin0, ns_e, nv_e);
    tp0_k<<<(E_EDGES * 64) / 256, 256, 0, stream>>>(fsg, fvg, ns_e, nv_e, eidx, ts, tv);
    launch_gemm(stream, 0, ts, 128, 128, nullptr, 0, 0, lin0_sw, 64, fs1, 64, E_EDGES, 64, nullptr);
    launch_gemm(stream, 0, tv, 128, 128, nullptr, 0, 0, lin0_vw, 64, fv1, 64, 3 * E_EDGES, 64, nullptr);

    // ---- latent update MLP + residual blend ----
    launch_gemm(stream, 1, lat, 256, 256, ts, 128, 128, lat1_w0, 256, hA, 256, E_EDGES, 256, nullptr);
    launch_gemm(stream, 0, hA, 256, 256, nullptr, 0, 0, lat1_w1, 256, hB, 256, E_EDGES, 256, nullptr);
    blend_k<<<(E_EDGES * 256) / 256, 256, 0, stream>>>(lat, hB, cut, res_p);

    // ---- stage C ----
    launch_gemm(stream, 0, lat, 256, 256, nullptr, 0, 0, env1_w, 192, wall, 192, E_EDGES, 192, nullptr);
    ew1_k<<<(E_EDGES * 64) / 256, 256, 0, stream>>>(wall, ang, eidx, fs1, fv1, ns2_raw, nv2_raw);
    nodelin_k<<<NNODES, 64, 0, stream>>>(ns2_raw, nv2_raw, envlin1, ns2_e, nv2_e);
    tp1_k<<<(E_EDGES * 64) / 256, 256, 0, stream>>>(fs1, fv1, ns2_e, nv2_e, eidx, ts, tv);
    launch_gemm(stream, 0, ts, 128, 128, nullptr, 0, 0, SWt, 128, fs2, 128, E_EDGES, 128, nullptr);
    launch_gemm(stream, 0, tv, 128, 128, nullptr, 0, 0, VWt, 128, fv2, 128, 3 * E_EDGES, 128, nullptr);

    // ---- final MLP + output ----
    launch_gemm(stream, 1, lat, 256, 256, ts, 128, 128, fin_w0, 256, hA, 256, E_EDGES, 256, nullptr);
    launch_gemm(stream, 0, hA, 256, 256, nullptr, 0, 0, fin_w1, 128, hB, 128, E_EDGES, 128, nullptr);
    out_k<<<(E_EDGES * 512) / 256, 256, 0, stream>>>(fs2, hB, fv2, (float*)d_out);
}

// Round 2
// 1908.173 us; speedup vs baseline: 1.5843x; 1.5843x over previous
//
#include <hip/hip_runtime.h>
#include <math.h>

typedef unsigned short u16;
typedef unsigned int   u32;

#define E_EDGES 100000
#define NNODES  5000
#define INV_SQRT3 0.57735026918962576f
#define INV_AVG   0.05f

typedef short bf16x8 __attribute__((ext_vector_type(8)));
typedef float f32x4  __attribute__((ext_vector_type(4)));

__device__ __forceinline__ float us2f(u16 u) {
    union { float f; u32 i; } c; c.i = ((u32)u) << 16; return c.f;
}
__device__ __forceinline__ u16 f2us(float f) {
    union { float f; u32 i; } c; c.f = f;
    u32 x = c.i;
    x += 0x7fffu + ((x >> 16) & 1u);   // round-to-nearest-even bf16
    return (u16)(x >> 16);
}
__device__ __forceinline__ float siluf(float x) { return x / (1.f + expf(-x)); }

__device__ __forceinline__ void gl_lds16(const void* g, void* l) {
    auto* s = (const __attribute__((address_space(1))) void*)g;
    auto* d = (__attribute__((address_space(3))) void*)l;
    __builtin_amdgcn_global_load_lds(s, d, 16, 0, 0);
}

// ---------------------------------------------------------------------------
// MFMA GEMM: Y(MxN,bf16) = epi( concat(X1,X2)(MxK,bf16) @ (W_hi+W_lo) )
// W_hi/W_lo stored transposed [n][k] (ldk = K). Block: 128 threads (2 waves),
// tile 128x64. Wave w computes rows w*64..w*64+63 x all 64 cols.
// LDS t-granule-major layout -> conflict-free ds_read_b128 frag reads, and
// global_load_lds bases are sequential 1KB chunks (wave-uniform).
// EPI: 0 none, 1 silu, 2 scale-by-cut[row]
// ---------------------------------------------------------------------------
template <int EPI>
__global__ __launch_bounds__(128) void mgemm_k(
    const u16* __restrict__ X1, int ldx1, int K1,
    const u16* __restrict__ X2, int ldx2, int K2,
    const u16* __restrict__ Wh, const u16* __restrict__ Wl, int ldk,
    u16* __restrict__ Y, int ldy, int M,
    const float* __restrict__ cut)
{
    __shared__ short lA[4096];    // 8KB : granule (t, row): offset shorts = t*1024 + row*8
    __shared__ short lBh[2048];   // 4KB : granule (t, col): offset shorts = t*512 + col*8
    __shared__ short lBl[2048];   // 4KB
    const int lane = threadIdx.x & 63;
    const int w    = threadIdx.x >> 6;    // wave 0..1
    const int q    = lane >> 4;           // quad 0..3 (k-granule t)
    const int r16  = lane & 15;
    const int m0 = blockIdx.x * 128;
    const int n0 = blockIdx.y * 64;
    const int Kt = K1 + K2;

    f32x4 acc[4][4];
#pragma unroll
    for (int i = 0; i < 4; ++i)
#pragma unroll
        for (int j = 0; j < 4; ++j) acc[i][j] = (f32x4){0.f, 0.f, 0.f, 0.f};

    for (int k0 = 0; k0 < Kt; k0 += 32) {
        const u16* xs; int ldx, kb;
        if (k0 < K1) { xs = X1; ldx = ldx1; kb = k0; }
        else         { xs = X2; ldx = ldx2; kb = k0 - K1; }
        // ---- stage A: instr j = w*4+i writes LDS bytes [j*1024, j*1024+1024) ----
        //      covers t = j>>1, rows (j&1)*64 + lane
#pragma unroll
        for (int i = 0; i < 4; ++i) {
            const int j = w * 4 + i;
            int row = m0 + (j & 1) * 64 + lane;
            row = row < M ? row : M - 1;                     // clamp OOB (result discarded)
            gl_lds16(xs + (size_t)row * ldx + kb + (j >> 1) * 8, &lA[j * 512]);
        }
        // ---- stage B: instr j = w*2+i : t = j, col = lane ----
#pragma unroll
        for (int i = 0; i < 2; ++i) {
            const int j = w * 2 + i;
            const size_t wo = (size_t)(n0 + lane) * ldk + k0 + j * 8;
            gl_lds16(Wh + wo, &lBh[j * 512]);
            gl_lds16(Wl + wo, &lBl[j * 512]);
        }
        __syncthreads();
        // ---- fragments ----
        bf16x8 a[4], bh[4], bl[4];
#pragma unroll
        for (int rt = 0; rt < 4; ++rt)
            a[rt] = *(const bf16x8*)&lA[q * 1024 + (w * 64 + rt * 16 + r16) * 8];
#pragma unroll
        for (int ct = 0; ct < 4; ++ct) {
            bh[ct] = *(const bf16x8*)&lBh[q * 512 + (ct * 16 + r16) * 8];
            bl[ct] = *(const bf16x8*)&lBl[q * 512 + (ct * 16 + r16) * 8];
        }
        // ---- MFMA: hi + lo compensation ----
#pragma unroll
        for (int rt = 0; rt < 4; ++rt)
#pragma unroll
            for (int ct = 0; ct < 4; ++ct) {
                acc[rt][ct] = __builtin_amdgcn_mfma_f32_16x16x32_bf16(a[rt], bh[ct], acc[rt][ct], 0, 0, 0);
                acc[rt][ct] = __builtin_amdgcn_mfma_f32_16x16x32_bf16(a[rt], bl[ct], acc[rt][ct], 0, 0, 0);
            }
        __syncthreads();
    }
    // ---- epilogue: D[row=(q*4+r) in tile][col=r16] ----
#pragma unroll
    for (int rt = 0; rt < 4; ++rt) {
#pragma unroll
        for (int r = 0; r < 4; ++r) {
            const int row = m0 + w * 64 + rt * 16 + q * 4 + r;
            if (row < M) {
                float sc = 1.f;
                if (EPI == 2) sc = cut[row];
#pragma unroll
                for (int ct = 0; ct < 4; ++ct) {
                    float v = acc[rt][ct][r];
                    if (EPI == 1) v = siluf(v);
                    if (EPI == 2) v *= sc;
                    Y[(size_t)row * ldy + n0 + ct * 16 + r16] = f2us(v);
                }
            }
        }
    }
}

// ---------------------------------------------------------------------------
// Weight prep: split f32 W (Ksrc x Nsrc row-major) into bf16 hi/lo, stored
// transposed [n][k] with k padded to Kpad (zeros beyond Ksrc).
// MODE 0: standard. MODE 1: lin1 (2,2,64,64) [i][o][u][v], k=i*64+u, n=o*64+v.
// ---------------------------------------------------------------------------
template <int MODE>
__global__ __launch_bounds__(256) void split_w_k(
    const float* __restrict__ src, u16* __restrict__ hi, u16* __restrict__ lo,
    int Ksrc, int Nsrc, int Kpad)
{
    int idx = blockIdx.x * 256 + threadIdx.x;
    if (idx >= Nsrc * Kpad) return;
    int n = idx / Kpad, k = idx - n * Kpad;
    float wv = 0.f;
    if (k < Ksrc) {
        if (MODE == 0) wv = src[(size_t)k * Nsrc + n];
        else           wv = src[(k >> 6) * 8192 + (n >> 6) * 4096 + (k & 63) * 64 + (n & 63)];
    }
    u16 h = f2us(wv);
    hi[idx] = h;
    lo[idx] = f2us(wv - us2f(h));
}

// ---------------------------------------------------------------------------
// prep: X0 = [node[center] | node[neigh] | radial | 0pad] (E x 160 bf16), cut
// ---------------------------------------------------------------------------
__global__ __launch_bounds__(256) void prep_edges_k(
    const float* __restrict__ na, const float* __restrict__ radial,
    const float* __restrict__ lengths, const int* __restrict__ eidx,
    u16* __restrict__ X0, float* __restrict__ cut)
{
    int idx = blockIdx.x * 256 + threadIdx.x;
    if (idx >= E_EDGES * 160) return;
    int e = idx / 160;
    int k = idx - e * 160;
    float v = 0.f;
    if (k < 64)       v = na[(size_t)eidx[e] * 64 + k];
    else if (k < 128) v = na[(size_t)eidx[E_EDGES + e] * 64 + (k - 64)];
    else if (k < 136) v = radial[(size_t)e * 8 + (k - 128)];
    X0[idx] = f2us(v);
    if (k == 136) {
        float x = lengths[e] * 0.2f;           // r / R_MAX
        float x3 = x * x * x;
        float x6 = x3 * x3, x7 = x6 * x, x8 = x7 * x;
        float o = 1.f - 28.f * x6 + 48.f * x7 - 21.f * x8;
        cut[e] = (x < 1.f) ? o : 0.f;
    }
}

// ---------------------------------------------------------------------------
// stage-B elementwise: split w_all0 (E x 320), gated feat fs/fv, env atomics
// ---------------------------------------------------------------------------
__global__ __launch_bounds__(256) void ew0_k(
    const u16* __restrict__ wall, const float* __restrict__ ang,
    const int* __restrict__ eidx,
    u16* __restrict__ fsg, u16* __restrict__ fvg,
    float* __restrict__ ns_raw, float* __restrict__ nv_raw)
{
    int idx = blockIdx.x * 256 + threadIdx.x;
    if (idx >= E_EDGES * 64) return;
    int e = idx >> 6, u = idx & 63;
    const u16* wr = wall + (size_t)e * 320;
    float we0 = us2f(wr[2 * u]),       we1 = us2f(wr[2 * u + 1]);
    float g   = us2f(wr[128 + u]);
    float wf0 = us2f(wr[192 + 2 * u]), wf1 = us2f(wr[193 + 2 * u]);
    float sh0 = ang[e * 4 + 0], sh1 = ang[e * 4 + 1];
    float sh2 = ang[e * 4 + 2], sh3 = ang[e * 4 + 3];
    fsg[idx] = f2us(wf0 * sh0 * g);
    fvg[(size_t)idx * 3 + 0] = f2us(wf1 * sh1 * g);
    fvg[(size_t)idx * 3 + 1] = f2us(wf1 * sh2 * g);
    fvg[(size_t)idx * 3 + 2] = f2us(wf1 * sh3 * g);
    int ce = eidx[e];
    atomicAdd(&ns_raw[ce * 64 + u], we0 * sh0);
    atomicAdd(&nv_raw[ce * 192 + u * 3 + 0], we1 * sh1);
    atomicAdd(&nv_raw[ce * 192 + u * 3 + 1], we1 * sh2);
    atomicAdd(&nv_raw[ce * 192 + u * 3 + 2], we1 * sh3);
}

// per-node: ns_e = (segsum/20) @ L0 ; nv_e[c] = (segsum/20) @ L1
__global__ __launch_bounds__(64) void nodelin_k(
    const float* __restrict__ ns_raw, const float* __restrict__ nv_raw,
    const float* __restrict__ envlin,
    float* __restrict__ ns_e, float* __restrict__ nv_e)
{
    __shared__ float ss[64];
    __shared__ float sv[192];
    int n = blockIdx.x, v = threadIdx.x;
    ss[v]        = ns_raw[n * 64 + v];
    sv[v]        = nv_raw[n * 192 + v];
    sv[64 + v]   = nv_raw[n * 192 + 64 + v];
    sv[128 + v]  = nv_raw[n * 192 + 128 + v];
    __syncthreads();
    const float* L0 = envlin;
    const float* L1 = envlin + 4096;
    float a0 = 0.f, a1 = 0.f, a2 = 0.f, a3 = 0.f;
#pragma unroll 8
    for (int u = 0; u < 64; ++u) {
        float l0 = L0[u * 64 + v], l1 = L1[u * 64 + v];
        a0 = fmaf(ss[u], l0, a0);
        a1 = fmaf(sv[u * 3 + 0], l1, a1);
        a2 = fmaf(sv[u * 3 + 1], l1, a2);
        a3 = fmaf(sv[u * 3 + 2], l1, a3);
    }
    ns_e[n * 64 + v]            = a0 * INV_AVG;
    nv_e[n * 192 + v]           = a1 * INV_AVG;
    nv_e[n * 192 + 64 + v]      = a2 * INV_AVG;
    nv_e[n * 192 + 128 + v]     = a3 * INV_AVG;
}

// tensor product uuu: ts (E x 128 [i*64+u]), tv (rows e*3+c, 128 cols)
__global__ __launch_bounds__(256) void tp0_k(
    const u16* __restrict__ fsg, const u16* __restrict__ fvg,
    const float* __restrict__ ns_e, const float* __restrict__ nv_e,
    const int* __restrict__ eidx, u16* __restrict__ ts, u16* __restrict__ tv)
{
    int idx = blockIdx.x * 256 + threadIdx.x;
    if (idx >= E_EDGES * 64) return;
    int e = idx >> 6, u = idx & 63;
    int ce = eidx[e];
    float f  = us2f(fsg[idx]);
    float b0 = us2f(fvg[(size_t)idx * 3 + 0]);
    float b1 = us2f(fvg[(size_t)idx * 3 + 1]);
    float b2 = us2f(fvg[(size_t)idx * 3 + 2]);
    float ns = ns_e[ce * 64 + u];
    float n0 = nv_e[ce * 192 + u], n1 = nv_e[ce * 192 + 64 + u], n2 = nv_e[ce * 192 + 128 + u];
    ts[(size_t)e * 128 + u]      = f2us(f * ns);
    ts[(size_t)e * 128 + 64 + u] = f2us((b0 * n0 + b1 * n1 + b2 * n2) * INV_SQRT3);
    size_t tb = (size_t)e * 384;
    tv[tb + u]             = f2us(f * n0 * INV_SQRT3);
    tv[tb + 128 + u]       = f2us(f * n1 * INV_SQRT3);
    tv[tb + 256 + u]       = f2us(f * n2 * INV_SQRT3);
    tv[tb + 64 + u]        = f2us(b0 * ns * INV_SQRT3);
    tv[tb + 128 + 64 + u]  = f2us(b1 * ns * INV_SQRT3);
    tv[tb + 256 + 64 + u]  = f2us(b2 * ns * INV_SQRT3);
}

// latents = sqrt(1-a)*latents + sqrt(a)*cut*new_lat (in place)
__global__ __launch_bounds__(256) void blend_k(
    u16* __restrict__ lat, const u16* __restrict__ nl,
    const float* __restrict__ cut, const float* __restrict__ resp)
{
    int idx = blockIdx.x * 256 + threadIdx.x;
    if (idx >= E_EDGES * 256) return;
    int e = idx >> 8;
    float a  = 1.f / (1.f + expf(-resp[1]));
    float c1 = sqrtf(1.f - a);
    float c2 = sqrtf(a) * cut[e];
    lat[idx] = f2us(c1 * us2f(lat[idx]) + c2 * us2f(nl[idx]));
}

// stage-C elementwise: gate fs1/fv1 in place, env atomics from w_all1 (E x 192)
__global__ __launch_bounds__(256) void ew1_k(
    const u16* __restrict__ wall, const float* __restrict__ ang,
    const int* __restrict__ eidx,
    u16* __restrict__ fs1, u16* __restrict__ fv1,
    float* __restrict__ ns_raw, float* __restrict__ nv_raw)
{
    int idx = blockIdx.x * 256 + threadIdx.x;
    if (idx >= E_EDGES * 64) return;
    int e = idx >> 6, u = idx & 63;
    const u16* wr = wall + (size_t)e * 192;
    float we0 = us2f(wr[2 * u]), we1 = us2f(wr[2 * u + 1]);
    float g   = us2f(wr[128 + u]);
    fs1[idx] = f2us(us2f(fs1[idx]) * g);
    size_t fb = (size_t)e * 192;
    fv1[fb + u]       = f2us(us2f(fv1[fb + u]) * g);
    fv1[fb + 64 + u]  = f2us(us2f(fv1[fb + 64 + u]) * g);
    fv1[fb + 128 + u] = f2us(us2f(fv1[fb + 128 + u]) * g);
    float sh0 = ang[e * 4 + 0], sh1 = ang[e * 4 + 1];
    float sh2 = ang[e * 4 + 2], sh3 = ang[e * 4 + 3];
    int ce = eidx[e];
    atomicAdd(&ns_raw[ce * 64 + u], we0 * sh0);
    atomicAdd(&nv_raw[ce * 192 + u * 3 + 0], we1 * sh1);
    atomicAdd(&nv_raw[ce * 192 + u * 3 + 1], we1 * sh2);
    atomicAdd(&nv_raw[ce * 192 + u * 3 + 2], we1 * sh3);
}

__global__ __launch_bounds__(256) void tp1_k(
    const u16* __restrict__ fs1, const u16* __restrict__ fv1,
    const float* __restrict__ ns_e, const float* __restrict__ nv_e,
    const int* __restrict__ eidx, u16* __restrict__ ts, u16* __restrict__ tv)
{
    int idx = blockIdx.x * 256 + threadIdx.x;
    if (idx >= E_EDGES * 64) return;
    int e = idx >> 6, u = idx & 63;
    int ce = eidx[e];
    float f = us2f(fs1[idx]);
    size_t fb = (size_t)e * 192;
    float b0 = us2f(fv1[fb + u]), b1 = us2f(fv1[fb + 64 + u]), b2 = us2f(fv1[fb + 128 + u]);
    float ns = ns_e[ce * 64 + u];
    float n0 = nv_e[ce * 192 + u], n1 = nv_e[ce * 192 + 64 + u], n2 = nv_e[ce * 192 + 128 + u];
    ts[(size_t)e * 128 + u]      = f2us(f * ns);
    ts[(size_t)e * 128 + 64 + u] = f2us((b0 * n0 + b1 * n1 + b2 * n2) * INV_SQRT3);
    size_t tb = (size_t)e * 384;
    tv[tb + u]             = f2us(f * n0 * INV_SQRT3);
    tv[tb + 128 + u]       = f2us(f * n1 * INV_SQRT3);
    tv[tb + 256 + u]       = f2us(f * n2 * INV_SQRT3);
    tv[tb + 64 + u]        = f2us(b0 * ns * INV_SQRT3);
    tv[tb + 128 + 64 + u]  = f2us(b1 * ns * INV_SQRT3);
    tv[tb + 256 + 64 + u]  = f2us(b2 * ns * INV_SQRT3);
}

// final assembly: out[e][0:128] = fs2*fin ; out[e][128+o*192+v*3+c] = fv2[e,c,o*64+v]
__global__ __launch_bounds__(256) void out_k(
    const u16* __restrict__ fs2, const u16* __restrict__ fin,
    const u16* __restrict__ fv2, float* __restrict__ out)
{
    int idx = blockIdx.x * 256 + threadIdx.x;
    if (idx >= E_EDGES * 512) return;
    int e = idx >> 9, j = idx & 511;
    float v;
    if (j < 128) {
        v = us2f(fs2[(size_t)e * 128 + j]) * us2f(fin[(size_t)e * 128 + j]);
    } else {
        int jj = j - 128;
        int o = (jj >= 192) ? 1 : 0;
        int rem = jj - o * 192;
        int vv = rem / 3;
        int c  = rem - vv * 3;
        v = us2f(fv2[(size_t)e * 384 + (size_t)c * 128 + o * 64 + vv]);
    }
    out[idx] = v;
}

// ---------------------------------------------------------------------------
static void mgemm(hipStream_t s, int epi,
                  const u16* X1, int ldx1, int K1,
                  const u16* X2, int ldx2, int K2,
                  const u16* Wh, const u16* Wl, int ldk,
                  u16* Y, int ldy, int M, int N,
                  const float* cut)
{
    dim3 grid((M + 127) / 128, N / 64);
    dim3 block(128);
    if (epi == 0)      mgemm_k<0><<<grid, block, 0, s>>>(X1, ldx1, K1, X2, ldx2, K2, Wh, Wl, ldk, Y, ldy, M, cut);
    else if (epi == 1) mgemm_k<1><<<grid, block, 0, s>>>(X1, ldx1, K1, X2, ldx2, K2, Wh, Wl, ldk, Y, ldy, M, cut);
    else               mgemm_k<2><<<grid, block, 0, s>>>(X1, ldx1, K1, X2, ldx2, K2, Wh, Wl, ldk, Y, ldy, M, cut);
}

static void split_w(hipStream_t s, int mode, const float* src, u16* hi, u16* lo,
                    int Ksrc, int Nsrc, int Kpad)
{
    int n = Nsrc * Kpad;
    dim3 grid((n + 255) / 256), block(256);
    if (mode == 0) split_w_k<0><<<grid, block, 0, s>>>(src, hi, lo, Ksrc, Nsrc, Kpad);
    else           split_w_k<1><<<grid, block, 0, s>>>(src, hi, lo, Ksrc, Nsrc, Kpad);
}

extern "C" void kernel_launch(void* const* d_in, const int* in_sizes, int n_in,
                              void* d_out, int out_size, void* d_ws, size_t ws_size,
                              hipStream_t stream)
{
    const float* node_attrs = (const float*)d_in[0];
    const float* radial     = (const float*)d_in[1];
    const float* ang        = (const float*)d_in[2];
    const float* lengths    = (const float*)d_in[3];
    const int*   eidx       = (const int*)d_in[4];
    const float* tb_w0      = (const float*)d_in[5];
    const float* tb_w1      = (const float*)d_in[6];
    const float* tb_w2      = (const float*)d_in[7];
    const float* lat1_w0    = (const float*)d_in[8];
    const float* lat1_w1    = (const float*)d_in[9];
    const float* env0_w     = (const float*)d_in[10];
    const float* env1_w     = (const float*)d_in[11];
    const float* envlin0    = (const float*)d_in[12];
    const float* envlin1    = (const float*)d_in[13];
    const float* lin0_sw    = (const float*)d_in[14];
    const float* lin0_vw    = (const float*)d_in[15];
    const float* lin1_sw    = (const float*)d_in[16];
    const float* lin1_vw    = (const float*)d_in[17];
    const float* fin_w0     = (const float*)d_in[18];
    const float* fin_w1     = (const float*)d_in[19];
    const float* res_p      = (const float*)d_in[20];

    const size_t E = E_EDGES;
    unsigned char* ws = (unsigned char*)d_ws;
    size_t off = 0;
    auto take = [&](size_t n) -> void* {
        void* p = ws + off;
        off += (n + 255) & ~(size_t)255;
        return p;
    };
    u16*  X0   = (u16*)take(E * 160 * 2);
    float* cut = (float*)take(E * 4);
    u16*  hA   = (u16*)take(E * 256 * 2);
    u16*  hB   = (u16*)take(E * 256 * 2);
    u16*  lat  = (u16*)take(E * 256 * 2);
    u16*  wall = (u16*)take(E * 320 * 2);   // reused for w_all1 (E x 192)
    u16*  fsg  = (u16*)take(E * 64 * 2);
    u16*  fvg  = (u16*)take(E * 192 * 2);
    u16*  ts   = (u16*)take(E * 128 * 2);   // reused for ts2
    u16*  tv   = (u16*)take(E * 384 * 2);   // reused for tv2
    u16*  fs1  = (u16*)take(E * 64 * 2);
    u16*  fv1  = (u16*)take(E * 192 * 2);
    u16*  fs2  = (u16*)take(E * 128 * 2);
    u16*  fv2  = (u16*)take(E * 384 * 2);
    float* nodebuf = (float*)take((size_t)NNODES * 256 * 4 * 2); // 2 stages of raw sums
    float* ns_raw  = nodebuf;
    float* nv_raw  = nodebuf + NNODES * 64;
    float* ns2_raw = nodebuf + NNODES * 256;
    float* nv2_raw = nodebuf + NNODES * 256 + NNODES * 64;
    float* ns_e  = (float*)take((size_t)NNODES * 64 * 4);
    float* nv_e  = (float*)take((size_t)NNODES * 192 * 4);
    float* ns2_e = (float*)take((size_t)NNODES * 64 * 4);
    float* nv2_e = (float*)take((size_t)NNODES * 192 * 4);

    // weight arena: transposed hi/lo bf16, k padded. sizes in elements:
    // W0 256x160, W1 256x256, W2 256x256, We0 320x256, WL0 256x384,
    // WL1 256x256, We1 192x256, S0 64x128, V0 64x128, S1 128x128,
    // V1 128x128, WF0 256x384, WF1 128x256
    u16* W0h  = (u16*)take(256 * 160 * 2); u16* W0l  = (u16*)take(256 * 160 * 2);
    u16* W1h  = (u16*)take(65536 * 2);     u16* W1l  = (u16*)take(65536 * 2);
    u16* W2h  = (u16*)take(65536 * 2);     u16* W2l  = (u16*)take(65536 * 2);
    u16* We0h = (u16*)take(81920 * 2);     u16* We0l = (u16*)take(81920 * 2);
    u16* WL0h = (u16*)take(98304 * 2);     u16* WL0l = (u16*)take(98304 * 2);
    u16* WL1h = (u16*)take(65536 * 2);     u16* WL1l = (u16*)take(65536 * 2);
    u16* We1h = (u16*)take(49152 * 2);     u16* We1l = (u16*)take(49152 * 2);
    u16* S0h  = (u16*)take(8192 * 2);      u16* S0l  = (u16*)take(8192 * 2);
    u16* V0h  = (u16*)take(8192 * 2);      u16* V0l  = (u16*)take(8192 * 2);
    u16* S1h  = (u16*)take(16384 * 2);     u16* S1l  = (u16*)take(16384 * 2);
    u16* V1h  = (u16*)take(16384 * 2);     u16* V1l  = (u16*)take(16384 * 2);
    u16* WF0h = (u16*)take(98304 * 2);     u16* WF0l = (u16*)take(98304 * 2);
    u16* WF1h = (u16*)take(32768 * 2);     u16* WF1l = (u16*)take(32768 * 2);

    hipMemsetAsync(nodebuf, 0, (size_t)NNODES * 256 * 4 * 2, stream);

    // ---- weight prep ----
    split_w(stream, 0, tb_w0,   W0h,  W0l,  136, 256, 160);
    split_w(stream, 0, tb_w1,   W1h,  W1l,  256, 256, 256);
    split_w(stream, 0, tb_w2,   W2h,  W2l,  256, 256, 256);
    split_w(stream, 0, env0_w,  We0h, We0l, 256, 320, 256);
    split_w(stream, 0, lat1_w0, WL0h, WL0l, 384, 256, 384);
    split_w(stream, 0, lat1_w1, WL1h, WL1l, 256, 256, 256);
    split_w(stream, 0, env1_w,  We1h, We1l, 256, 192, 256);
    split_w(stream, 0, lin0_sw, S0h,  S0l,  128, 64,  128);
    split_w(stream, 0, lin0_vw, V0h,  V0l,  128, 64,  128);
    split_w(stream, 1, lin1_sw, S1h,  S1l,  128, 128, 128);
    split_w(stream, 1, lin1_vw, V1h,  V1l,  128, 128, 128);
    split_w(stream, 0, fin_w0,  WF0h, WF0l, 384, 256, 384);
    split_w(stream, 0, fin_w1,  WF1h, WF1l, 256, 128, 256);

    prep_edges_k<<<(E_EDGES * 160) / 256, 256, 0, stream>>>(node_attrs, radial, lengths, eidx, X0, cut);

    // ---- stage A: two-body MLP -> latents ----
    mgemm(stream, 1, X0, 160, 160, nullptr, 0, 0, W0h, W0l, 160, hA, 256, E_EDGES, 256, nullptr);
    mgemm(stream, 1, hA, 256, 256, nullptr, 0, 0, W1h, W1l, 256, hB, 256, E_EDGES, 256, nullptr);
    mgemm(stream, 2, hB, 256, 256, nullptr, 0, 0, W2h, W2l, 256, lat, 256, E_EDGES, 256, cut);

    // ---- stage B ----
    mgemm(stream, 0, lat, 256, 256, nullptr, 0, 0, We0h, We0l, 256, wall, 320, E_EDGES, 320, nullptr);
    ew0_k<<<(E_EDGES * 64) / 256, 256, 0, stream>>>(wall, ang, eidx, fsg, fvg, ns_raw, nv_raw);
    nodelin_k<<<NNODES, 64, 0, stream>>>(ns_raw, nv_raw, envlin0, ns_e, nv_e);
    tp0_k<<<(E_EDGES * 64) / 256, 256, 0, stream>>>(fsg, fvg, ns_e, nv_e, eidx, ts, tv);
    mgemm(stream, 0, ts, 128, 128, nullptr, 0, 0, S0h, S0l, 128, fs1, 64, E_EDGES, 64, nullptr);
    mgemm(stream, 0, tv, 128, 128, nullptr, 0, 0, V0h, V0l, 128, fv1, 64, 3 * E_EDGES, 64, nullptr);

    // ---- latent update MLP + residual blend ----
    mgemm(stream, 1, lat, 256, 256, ts, 128, 128, WL0h, WL0l, 384, hA, 256, E_EDGES, 256, nullptr);
    mgemm(stream, 0, hA, 256, 256, nullptr, 0, 0, WL1h, WL1l, 256, hB, 256, E_EDGES, 256, nullptr);
    blend_k<<<(E_EDGES * 256) / 256, 256, 0, stream>>>(lat, hB, cut, res_p);

    // ---- stage C ----
    mgemm(stream, 0, lat, 256, 256, nullptr, 0, 0, We1h, We1l, 256, wall, 192, E_EDGES, 192, nullptr);
    ew1_k<<<(E_EDGES * 64) / 256, 256, 0, stream>>>(wall, ang, eidx, fs1, fv1, ns2_raw, nv2_raw);
    nodelin_k<<<NNODES, 64, 0, stream>>>(ns2_raw, nv2_raw, envlin1, ns2_e, nv2_e);
    tp1_k<<<(E_EDGES * 64) / 256, 256, 0, stream>>>(fs1, fv1, ns2_e, nv2_e, eidx, ts, tv);
    mgemm(stream, 0, ts, 128, 128, nullptr, 0, 0, S1h, S1l, 128, fs2, 128, E_EDGES, 128, nullptr);
    mgemm(stream, 0, tv, 128, 128, nullptr, 0, 0, V1h, V1l, 128, fv2, 128, 3 * E_EDGES, 128, nullptr);

    // ---- final MLP + output ----
    mgemm(stream, 1, lat, 256, 256, ts, 128, 128, WF0h, WF0l, 384, hA, 256, E_EDGES, 256, nullptr);
    mgemm(stream, 0, hA, 256, 256, nullptr, 0, 0, WF1h, WF1l, 256, hB, 128, E_EDGES, 128, nullptr);
    out_k<<<(E_EDGES * 512) / 256, 256, 0, stream>>>(fs2, hB, fv2, (float*)d_out);
}

// Round 3
// 1419.502 us; speedup vs baseline: 2.1297x; 1.3443x over previous
//
#include <hip/hip_runtime.h>
#include <math.h>

typedef unsigned short u16;
typedef unsigned int   u32;

#define E_EDGES 100000
#define NNODES  5000
#define INV_SQRT3 0.57735026918962576f
#define INV_AVG   0.05f

typedef short bf16x8 __attribute__((ext_vector_type(8)));
typedef float f32x4  __attribute__((ext_vector_type(4)));

__device__ __forceinline__ float us2f(u16 u) {
    union { float f; u32 i; } c; c.i = ((u32)u) << 16; return c.f;
}
__device__ __forceinline__ u16 f2us(float f) {
    union { float f; u32 i; } c; c.f = f;
    u32 x = c.i;
    x += 0x7fffu + ((x >> 16) & 1u);   // round-to-nearest-even bf16
    return (u16)(x >> 16);
}
__device__ __forceinline__ float siluf(float x) { return x / (1.f + expf(-x)); }

__device__ __forceinline__ void gl_lds16(const void* g, void* l) {
    auto* s = (const __attribute__((address_space(1))) void*)g;
    auto* d = (__attribute__((address_space(3))) void*)l;
    __builtin_amdgcn_global_load_lds(s, d, 16, 0, 0);
}

// ---------------------------------------------------------------------------
// MFMA GEMM, 4 waves, tile 128x128: Y = epi( concat(X1,X2) @ (W_hi+W_lo) )
// W stored transposed [n][k], n padded to >= grid cols, k padded to mult 32.
// Wave w: rows (w>>1)*64.., cols (w&1)*64..  (4x4 frags of 16x16).
// LDS t-granule-major: lA[(t,row)] = t*1024 + row*8 shorts (conflict pattern
// identical to the R2-verified kernel). Staging: 8 chunks of 1KB each for
// A / Bh / Bl, chunk j handled by wave j>>1.
// EPI: 0 none, 1 silu, 2 cut-scale, 3 residual blend (reads old Y, cut, resp)
// ---------------------------------------------------------------------------
template <int EPI>
__global__ __launch_bounds__(256) void mgemm2_k(
    const u16* __restrict__ X1, int ldx1, int K1,
    const u16* __restrict__ X2, int ldx2, int K2,
    const u16* __restrict__ Wh, const u16* __restrict__ Wl, int ldk,
    u16* __restrict__ Y, int ldy, int M, int N,
    const float* __restrict__ cut, const float* __restrict__ resp)
{
    __shared__ short lA[4096];    // 8KB : (t,row) t<4, row<128
    __shared__ short lBh[4096];   // 8KB : (t,col)
    __shared__ short lBl[4096];   // 8KB
    const int lane = threadIdx.x & 63;
    const int w    = threadIdx.x >> 6;    // wave 0..3
    const int q    = lane >> 4;           // k-granule
    const int r16  = lane & 15;
    const int m0 = blockIdx.x * 128;
    const int n0 = blockIdx.y * 128;
    const int wr0 = (w >> 1) * 64;        // wave row base in tile
    const int wc0 = (w & 1) * 64;         // wave col base in tile
    const int Kt = K1 + K2;

    f32x4 acc[4][4];
#pragma unroll
    for (int i = 0; i < 4; ++i)
#pragma unroll
        for (int j = 0; j < 4; ++j) acc[i][j] = (f32x4){0.f, 0.f, 0.f, 0.f};

    for (int k0 = 0; k0 < Kt; k0 += 32) {
        const u16* xs; int ldx, kb;
        if (k0 < K1) { xs = X1; ldx = ldx1; kb = k0; }
        else         { xs = X2; ldx = ldx2; kb = k0 - K1; }
        // ---- stage A: chunk j = w*2+i : t=j>>1, rows (j&1)*64+lane ----
#pragma unroll
        for (int i = 0; i < 2; ++i) {
            const int j = w * 2 + i;
            int row = m0 + (j & 1) * 64 + lane;
            row = row < M ? row : M - 1;                 // clamp OOB (discarded)
            gl_lds16(xs + (size_t)row * ldx + kb + (j >> 1) * 8, &lA[j * 512]);
        }
        // ---- stage B hi/lo: same chunk mapping over cols ----
#pragma unroll
        for (int i = 0; i < 2; ++i) {
            const int j = w * 2 + i;
            const size_t wo = (size_t)(n0 + (j & 1) * 64 + lane) * ldk + k0 + (j >> 1) * 8;
            gl_lds16(Wh + wo, &lBh[j * 512]);
            gl_lds16(Wl + wo, &lBl[j * 512]);
        }
        __syncthreads();
        bf16x8 a[4], bh[4], bl[4];
#pragma unroll
        for (int rt = 0; rt < 4; ++rt)
            a[rt] = *(const bf16x8*)&lA[q * 1024 + (wr0 + rt * 16 + r16) * 8];
#pragma unroll
        for (int ct = 0; ct < 4; ++ct) {
            bh[ct] = *(const bf16x8*)&lBh[q * 1024 + (wc0 + ct * 16 + r16) * 8];
            bl[ct] = *(const bf16x8*)&lBl[q * 1024 + (wc0 + ct * 16 + r16) * 8];
        }
#pragma unroll
        for (int rt = 0; rt < 4; ++rt)
#pragma unroll
            for (int ct = 0; ct < 4; ++ct) {
                acc[rt][ct] = __builtin_amdgcn_mfma_f32_16x16x32_bf16(a[rt], bh[ct], acc[rt][ct], 0, 0, 0);
                acc[rt][ct] = __builtin_amdgcn_mfma_f32_16x16x32_bf16(a[rt], bl[ct], acc[rt][ct], 0, 0, 0);
            }
        __syncthreads();
    }
    // ---- epilogue ----
    float c1 = 0.f, c2a = 0.f;
    if (EPI == 3) {
        float aa = 1.f / (1.f + expf(-resp[1]));
        c1 = sqrtf(1.f - aa);
        c2a = sqrtf(aa);
    }
#pragma unroll
    for (int rt = 0; rt < 4; ++rt) {
#pragma unroll
        for (int r = 0; r < 4; ++r) {
            const int row = m0 + wr0 + rt * 16 + q * 4 + r;
            if (row < M) {
                float sc = 1.f;
                if (EPI == 2) sc = cut[row];
                float c2 = 0.f;
                if (EPI == 3) c2 = c2a * cut[row];
#pragma unroll
                for (int ct = 0; ct < 4; ++ct) {
                    const int col = n0 + wc0 + ct * 16 + r16;
                    if (col < N) {
                        float v = acc[rt][ct][r];
                        if (EPI == 1) v = siluf(v);
                        if (EPI == 2) v *= sc;
                        if (EPI == 3) v = c1 * us2f(Y[(size_t)row * ldy + col]) + c2 * v;
                        Y[(size_t)row * ldy + col] = f2us(v);
                    }
                }
            }
        }
    }
}

// ---------------------------------------------------------------------------
// 2-wave 128x64 variant (used for the N=64 lin0 GEMMs) — verified in R2.
// ---------------------------------------------------------------------------
__global__ __launch_bounds__(128) void mgemm_k(
    const u16* __restrict__ X1, int ldx1, int K1,
    const u16* __restrict__ Wh, const u16* __restrict__ Wl, int ldk,
    u16* __restrict__ Y, int ldy, int M)
{
    __shared__ short lA[4096];
    __shared__ short lBh[2048];
    __shared__ short lBl[2048];
    const int lane = threadIdx.x & 63;
    const int w    = threadIdx.x >> 6;
    const int q    = lane >> 4;
    const int r16  = lane & 15;
    const int m0 = blockIdx.x * 128;
    const int n0 = blockIdx.y * 64;
    const int Kt = K1;

    f32x4 acc[4][4];
#pragma unroll
    for (int i = 0; i < 4; ++i)
#pragma unroll
        for (int j = 0; j < 4; ++j) acc[i][j] = (f32x4){0.f, 0.f, 0.f, 0.f};

    for (int k0 = 0; k0 < Kt; k0 += 32) {
#pragma unroll
        for (int i = 0; i < 4; ++i) {
            const int j = w * 4 + i;
            int row = m0 + (j & 1) * 64 + lane;
            row = row < M ? row : M - 1;
            gl_lds16(X1 + (size_t)row * ldx1 + k0 + (j >> 1) * 8, &lA[j * 512]);
        }
#pragma unroll
        for (int i = 0; i < 2; ++i) {
            const int j = w * 2 + i;
            const size_t wo = (size_t)(n0 + lane) * ldk + k0 + j * 8;
            gl_lds16(Wh + wo, &lBh[j * 512]);
            gl_lds16(Wl + wo, &lBl[j * 512]);
        }
        __syncthreads();
        bf16x8 a[4], bh[4], bl[4];
#pragma unroll
        for (int rt = 0; rt < 4; ++rt)
            a[rt] = *(const bf16x8*)&lA[q * 1024 + (w * 64 + rt * 16 + r16) * 8];
#pragma unroll
        for (int ct = 0; ct < 4; ++ct) {
            bh[ct] = *(const bf16x8*)&lBh[q * 512 + (ct * 16 + r16) * 8];
            bl[ct] = *(const bf16x8*)&lBl[q * 512 + (ct * 16 + r16) * 8];
        }
#pragma unroll
        for (int rt = 0; rt < 4; ++rt)
#pragma unroll
            for (int ct = 0; ct < 4; ++ct) {
                acc[rt][ct] = __builtin_amdgcn_mfma_f32_16x16x32_bf16(a[rt], bh[ct], acc[rt][ct], 0, 0, 0);
                acc[rt][ct] = __builtin_amdgcn_mfma_f32_16x16x32_bf16(a[rt], bl[ct], acc[rt][ct], 0, 0, 0);
            }
        __syncthreads();
    }
#pragma unroll
    for (int rt = 0; rt < 4; ++rt) {
#pragma unroll
        for (int r = 0; r < 4; ++r) {
            const int row = m0 + w * 64 + rt * 16 + q * 4 + r;
            if (row < M) {
#pragma unroll
                for (int ct = 0; ct < 4; ++ct)
                    Y[(size_t)row * ldy + n0 + ct * 16 + r16] = f2us(acc[rt][ct][r]);
            }
        }
    }
}

// ---------------------------------------------------------------------------
// Weight prep: f32 W (Ksrc x Nsrc row-major) -> bf16 hi/lo transposed [n][k],
// padded to Npad x Kpad with zeros.
// MODE 0: standard. MODE 1: lin1 (2,2,64,64) [i][o][u][v], k=i*64+u, n=o*64+v.
// ---------------------------------------------------------------------------
template <int MODE>
__global__ __launch_bounds__(256) void split_w_k(
    const float* __restrict__ src, u16* __restrict__ hi, u16* __restrict__ lo,
    int Ksrc, int Nsrc, int Kpad, int Npad)
{
    int idx = blockIdx.x * 256 + threadIdx.x;
    if (idx >= Npad * Kpad) return;
    int n = idx / Kpad, k = idx - n * Kpad;
    float wv = 0.f;
    if (k < Ksrc && n < Nsrc) {
        if (MODE == 0) wv = src[(size_t)k * Nsrc + n];
        else           wv = src[(k >> 6) * 8192 + (n >> 6) * 4096 + (k & 63) * 64 + (n & 63)];
    }
    u16 h = f2us(wv);
    hi[idx] = h;
    lo[idx] = f2us(wv - us2f(h));
}

// ---------------------------------------------------------------------------
// prep: X0 = [node[center] | node[neigh] | radial | 0pad] (E x 160 bf16), cut
// ---------------------------------------------------------------------------
__global__ __launch_bounds__(256) void prep_edges_k(
    const float* __restrict__ na, const float* __restrict__ radial,
    const float* __restrict__ lengths, const int* __restrict__ eidx,
    u16* __restrict__ X0, float* __restrict__ cut)
{
    int idx = blockIdx.x * 256 + threadIdx.x;
    if (idx >= E_EDGES * 160) return;
    int e = idx / 160;
    int k = idx - e * 160;
    float v = 0.f;
    if (k < 64)       v = na[(size_t)eidx[e] * 64 + k];
    else if (k < 128) v = na[(size_t)eidx[E_EDGES + e] * 64 + (k - 64)];
    else if (k < 136) v = radial[(size_t)e * 8 + (k - 128)];
    X0[idx] = f2us(v);
    if (k == 136) {
        float x = lengths[e] * 0.2f;           // r / R_MAX
        float x3 = x * x * x;
        float x6 = x3 * x3, x7 = x6 * x, x8 = x7 * x;
        float o = 1.f - 28.f * x6 + 48.f * x7 - 21.f * x8;
        cut[e] = (x < 1.f) ? o : 0.f;
    }
}

// ---------------------------------------------------------------------------
// counting sort of edges by center node
// ---------------------------------------------------------------------------
__global__ __launch_bounds__(256) void hist_k(const int* __restrict__ eidx, int* __restrict__ cnt)
{
    int e = blockIdx.x * 256 + threadIdx.x;
    if (e < E_EDGES) atomicAdd(&cnt[eidx[e]], 1);
}

__global__ __launch_bounds__(256) void scan_k(const int* __restrict__ cnt, int* __restrict__ offs)
{
    __shared__ int buf[256];
    __shared__ int base;
    if (threadIdx.x == 0) base = 0;
    __syncthreads();
    for (int start = 0; start < NNODES; start += 256) {
        int i = start + threadIdx.x;
        int v = (i < NNODES) ? cnt[i] : 0;
        buf[threadIdx.x] = v;
        __syncthreads();
        for (int d = 1; d < 256; d <<= 1) {
            int t = (threadIdx.x >= d) ? buf[threadIdx.x - d] : 0;
            __syncthreads();
            buf[threadIdx.x] += t;
            __syncthreads();
        }
        if (i < NNODES) offs[i] = base + buf[threadIdx.x] - v;
        __syncthreads();
        if (threadIdx.x == 255) base += buf[255];
        __syncthreads();
    }
}

__global__ __launch_bounds__(256) void scatter_k(
    const int* __restrict__ eidx, const int* __restrict__ offs,
    int* __restrict__ cur, int* __restrict__ perm)
{
    int e = blockIdx.x * 256 + threadIdx.x;
    if (e >= E_EDGES) return;
    int n = eidx[e];
    int p = atomicAdd(&cur[n], 1);
    perm[offs[n] + p] = e;
}

// ---------------------------------------------------------------------------
// per-node env segment-sum + envlin (replaces atomics + nodelin)
// LD = wall row stride (320 stage B, 192 stage C); env weights at cols [0,128)
// ---------------------------------------------------------------------------
template <int LD>
__global__ __launch_bounds__(64) void envsum_k(
    const u16* __restrict__ wall, const float* __restrict__ ang,
    const int* __restrict__ perm, const int* __restrict__ offs, const int* __restrict__ cnt,
    const float* __restrict__ envlin,
    float* __restrict__ ns_e, float* __restrict__ nv_e)
{
    const int n = blockIdx.x, lane = threadIdx.x;
    const int s = offs[n], c = cnt[n];
    float a0 = 0.f, a1 = 0.f, a2 = 0.f, a3 = 0.f;
    for (int i = 0; i < c; ++i) {
        int e = perm[s + i];
        u32 pw = *(const u32*)(wall + (size_t)e * LD + 2 * lane);
        float we0 = us2f((u16)(pw & 0xffffu)), we1 = us2f((u16)(pw >> 16));
        float4 sh = *(const float4*)(ang + (size_t)e * 4);
        a0 = fmaf(we0, sh.x, a0);
        a1 = fmaf(we1, sh.y, a1);
        a2 = fmaf(we1, sh.z, a2);
        a3 = fmaf(we1, sh.w, a3);
    }
    __shared__ float ss[64], sv0[64], sv1[64], sv2[64];
    ss[lane] = a0; sv0[lane] = a1; sv1[lane] = a2; sv2[lane] = a3;
    __syncthreads();
    const float* L0 = envlin;
    const float* L1 = envlin + 4096;
    float b0 = 0.f, b1 = 0.f, b2 = 0.f, b3 = 0.f;
#pragma unroll 8
    for (int u = 0; u < 64; ++u) {
        float l0 = L0[u * 64 + lane], l1 = L1[u * 64 + lane];
        b0 = fmaf(ss[u],  l0, b0);
        b1 = fmaf(sv0[u], l1, b1);
        b2 = fmaf(sv1[u], l1, b2);
        b3 = fmaf(sv2[u], l1, b3);
    }
    ns_e[n * 64 + lane]           = b0 * INV_AVG;
    nv_e[n * 192 + lane]          = b1 * INV_AVG;
    nv_e[n * 192 + 64 + lane]     = b2 * INV_AVG;
    nv_e[n * 192 + 128 + lane]    = b3 * INV_AVG;
}

// ---------------------------------------------------------------------------
// stage-B fused gate + tensor product (reads wall directly, no fsg/fvg)
// ---------------------------------------------------------------------------
__global__ __launch_bounds__(256) void tp0f_k(
    const u16* __restrict__ wall, const float* __restrict__ ang,
    const float* __restrict__ ns_e, const float* __restrict__ nv_e,
    const int* __restrict__ eidx, u16* __restrict__ ts, u16* __restrict__ tv)
{
    int idx = blockIdx.x * 256 + threadIdx.x;
    if (idx >= E_EDGES * 64) return;
    int e = idx >> 6, u = idx & 63;
    int ce = eidx[e];
    const u16* wr = wall + (size_t)e * 320;
    float g   = us2f(wr[128 + u]);
    u32 pw = *(const u32*)&wr[192 + 2 * u];
    float wf0 = us2f((u16)(pw & 0xffffu)), wf1 = us2f((u16)(pw >> 16));
    float4 sh = *(const float4*)(ang + (size_t)e * 4);
    float f  = wf0 * sh.x * g;
    float b0 = wf1 * sh.y * g;
    float b1 = wf1 * sh.z * g;
    float b2 = wf1 * sh.w * g;
    float ns = ns_e[ce * 64 + u];
    float n0 = nv_e[ce * 192 + u], n1 = nv_e[ce * 192 + 64 + u], n2 = nv_e[ce * 192 + 128 + u];
    ts[(size_t)e * 128 + u]      = f2us(f * ns);
    ts[(size_t)e * 128 + 64 + u] = f2us((b0 * n0 + b1 * n1 + b2 * n2) * INV_SQRT3);
    size_t tb = (size_t)e * 384;
    tv[tb + u]             = f2us(f * n0 * INV_SQRT3);
    tv[tb + 128 + u]       = f2us(f * n1 * INV_SQRT3);
    tv[tb + 256 + u]       = f2us(f * n2 * INV_SQRT3);
    tv[tb + 64 + u]        = f2us(b0 * ns * INV_SQRT3);
    tv[tb + 128 + 64 + u]  = f2us(b1 * ns * INV_SQRT3);
    tv[tb + 256 + 64 + u]  = f2us(b2 * ns * INV_SQRT3);
}

// ---------------------------------------------------------------------------
// stage-C fused gate + tensor product (gates lin0 outputs fs1/fv1 on the fly)
// ---------------------------------------------------------------------------
__global__ __launch_bounds__(256) void tp1f_k(
    const u16* __restrict__ fs1, const u16* __restrict__ fv1,
    const u16* __restrict__ wall,
    const float* __restrict__ ns_e, const float* __restrict__ nv_e,
    const int* __restrict__ eidx, u16* __restrict__ ts, u16* __restrict__ tv)
{
    int idx = blockIdx.x * 256 + threadIdx.x;
    if (idx >= E_EDGES * 64) return;
    int e = idx >> 6, u = idx & 63;
    int ce = eidx[e];
    float g = us2f(wall[(size_t)e * 192 + 128 + u]);
    float f  = us2f(fs1[(size_t)e * 64 + u]) * g;
    float b0 = us2f(fv1[((size_t)e * 3 + 0) * 64 + u]) * g;
    float b1 = us2f(fv1[((size_t)e * 3 + 1) * 64 + u]) * g;
    float b2 = us2f(fv1[((size_t)e * 3 + 2) * 64 + u]) * g;
    float ns = ns_e[ce * 64 + u];
    float n0 = nv_e[ce * 192 + u], n1 = nv_e[ce * 192 + 64 + u], n2 = nv_e[ce * 192 + 128 + u];
    ts[(size_t)e * 128 + u]      = f2us(f * ns);
    ts[(size_t)e * 128 + 64 + u] = f2us((b0 * n0 + b1 * n1 + b2 * n2) * INV_SQRT3);
    size_t tb = (size_t)e * 384;
    tv[tb + u]             = f2us(f * n0 * INV_SQRT3);
    tv[tb + 128 + u]       = f2us(f * n1 * INV_SQRT3);
    tv[tb + 256 + u]       = f2us(f * n2 * INV_SQRT3);
    tv[tb + 64 + u]        = f2us(b0 * ns * INV_SQRT3);
    tv[tb + 128 + 64 + u]  = f2us(b1 * ns * INV_SQRT3);
    tv[tb + 256 + 64 + u]  = f2us(b2 * ns * INV_SQRT3);
}

// final assembly: out[e][0:128] = fs2*fin ; out[e][128+o*192+v*3+c] = fv2[e,c,o*64+v]
__global__ __launch_bounds__(256) void out_k(
    const u16* __restrict__ fs2, const u16* __restrict__ fin,
    const u16* __restrict__ fv2, float* __restrict__ out)
{
    int idx = blockIdx.x * 256 + threadIdx.x;
    if (idx >= E_EDGES * 512) return;
    int e = idx >> 9, j = idx & 511;
    float v;
    if (j < 128) {
        v = us2f(fs2[(size_t)e * 128 + j]) * us2f(fin[(size_t)e * 128 + j]);
    } else {
        int jj = j - 128;
        int o = (jj >= 192) ? 1 : 0;
        int rem = jj - o * 192;
        int vv = rem / 3;
        int c  = rem - vv * 3;
        v = us2f(fv2[(size_t)e * 384 + (size_t)c * 128 + o * 64 + vv]);
    }
    out[idx] = v;
}

// ---------------------------------------------------------------------------
static void mgemm2(hipStream_t s, int epi,
                   const u16* X1, int ldx1, int K1,
                   const u16* X2, int ldx2, int K2,
                   const u16* Wh, const u16* Wl, int ldk,
                   u16* Y, int ldy, int M, int N,
                   const float* cut, const float* resp)
{
    dim3 grid((M + 127) / 128, (N + 127) / 128);
    dim3 block(256);
    if (epi == 0)      mgemm2_k<0><<<grid, block, 0, s>>>(X1, ldx1, K1, X2, ldx2, K2, Wh, Wl, ldk, Y, ldy, M, N, cut, resp);
    else if (epi == 1) mgemm2_k<1><<<grid, block, 0, s>>>(X1, ldx1, K1, X2, ldx2, K2, Wh, Wl, ldk, Y, ldy, M, N, cut, resp);
    else if (epi == 2) mgemm2_k<2><<<grid, block, 0, s>>>(X1, ldx1, K1, X2, ldx2, K2, Wh, Wl, ldk, Y, ldy, M, N, cut, resp);
    else               mgemm2_k<3><<<grid, block, 0, s>>>(X1, ldx1, K1, X2, ldx2, K2, Wh, Wl, ldk, Y, ldy, M, N, cut, resp);
}

static void split_w(hipStream_t s, int mode, const float* src, u16* hi, u16* lo,
                    int Ksrc, int Nsrc, int Kpad, int Npad)
{
    int n = Npad * Kpad;
    dim3 grid((n + 255) / 256), block(256);
    if (mode == 0) split_w_k<0><<<grid, block, 0, s>>>(src, hi, lo, Ksrc, Nsrc, Kpad, Npad);
    else           split_w_k<1><<<grid, block, 0, s>>>(src, hi, lo, Ksrc, Nsrc, Kpad, Npad);
}

extern "C" void kernel_launch(void* const* d_in, const int* in_sizes, int n_in,
                              void* d_out, int out_size, void* d_ws, size_t ws_size,
                              hipStream_t stream)
{
    const float* node_attrs = (const float*)d_in[0];
    const float* radial     = (const float*)d_in[1];
    const float* ang        = (const float*)d_in[2];
    const float* lengths    = (const float*)d_in[3];
    const int*   eidx       = (const int*)d_in[4];
    const float* tb_w0      = (const float*)d_in[5];
    const float* tb_w1      = (const float*)d_in[6];
    const float* tb_w2      = (const float*)d_in[7];
    const float* lat1_w0    = (const float*)d_in[8];
    const float* lat1_w1    = (const float*)d_in[9];
    const float* env0_w     = (const float*)d_in[10];
    const float* env1_w     = (const float*)d_in[11];
    const float* envlin0    = (const float*)d_in[12];
    const float* envlin1    = (const float*)d_in[13];
    const float* lin0_sw    = (const float*)d_in[14];
    const float* lin0_vw    = (const float*)d_in[15];
    const float* lin1_sw    = (const float*)d_in[16];
    const float* lin1_vw    = (const float*)d_in[17];
    const float* fin_w0     = (const float*)d_in[18];
    const float* fin_w1     = (const float*)d_in[19];
    const float* res_p      = (const float*)d_in[20];

    const size_t E = E_EDGES;
    unsigned char* ws = (unsigned char*)d_ws;
    size_t off = 0;
    auto take = [&](size_t n) -> void* {
        void* p = ws + off;
        off += (n + 255) & ~(size_t)255;
        return p;
    };
    u16*  X0   = (u16*)take(E * 160 * 2);
    float* cut = (float*)take(E * 4);
    u16*  hA   = (u16*)take(E * 256 * 2);
    u16*  hB   = (u16*)take(E * 256 * 2);
    u16*  lat  = (u16*)take(E * 256 * 2);
    u16*  wall = (u16*)take(E * 320 * 2);   // reused for w_all1 (E x 192)
    u16*  ts   = (u16*)take(E * 128 * 2);   // reused for ts2
    u16*  tv   = (u16*)take(E * 384 * 2);   // reused for tv2
    u16*  fs1  = (u16*)take(E * 64 * 2);
    u16*  fv1  = (u16*)take(E * 192 * 2);
    u16*  fs2  = (u16*)take(E * 128 * 2);
    u16*  fv2  = (u16*)take(E * 384 * 2);
    float* ns_e  = (float*)take((size_t)NNODES * 64 * 4);
    float* nv_e  = (float*)take((size_t)NNODES * 192 * 4);
    float* ns2_e = (float*)take((size_t)NNODES * 64 * 4);
    float* nv2_e = (float*)take((size_t)NNODES * 192 * 4);

    // sort scratch
    int* cnt  = (int*)take(NNODES * 4);
    int* cur  = (int*)take(NNODES * 4);
    int* offs = (int*)take(NNODES * 4);
    int* perm = (int*)take(E * 4);

    // weight arena: transposed hi/lo bf16, [Npad][Kpad]
    u16* W0h  = (u16*)take(256 * 160 * 2); u16* W0l  = (u16*)take(256 * 160 * 2);
    u16* W1h  = (u16*)take(65536 * 2);     u16* W1l  = (u16*)take(65536 * 2);
    u16* W2h  = (u16*)take(65536 * 2);     u16* W2l  = (u16*)take(65536 * 2);
    u16* We0h = (u16*)take(384 * 256 * 2); u16* We0l = (u16*)take(384 * 256 * 2);
    u16* WL0h = (u16*)take(98304 * 2);     u16* WL0l = (u16*)take(98304 * 2);
    u16* WL1h = (u16*)take(65536 * 2);     u16* WL1l = (u16*)take(65536 * 2);
    u16* We1h = (u16*)take(256 * 256 * 2); u16* We1l = (u16*)take(256 * 256 * 2);
    u16* S0h  = (u16*)take(8192 * 2);      u16* S0l  = (u16*)take(8192 * 2);
    u16* V0h  = (u16*)take(8192 * 2);      u16* V0l  = (u16*)take(8192 * 2);
    u16* S1h  = (u16*)take(16384 * 2);     u16* S1l  = (u16*)take(16384 * 2);
    u16* V1h  = (u16*)take(16384 * 2);     u16* V1l  = (u16*)take(16384 * 2);
    u16* WF0h = (u16*)take(98304 * 2);     u16* WF0l = (u16*)take(98304 * 2);
    u16* WF1h = (u16*)take(32768 * 2);     u16* WF1l = (u16*)take(32768 * 2);

    // zero sort counters (ws is re-poisoned before every call)
    hipMemsetAsync(cnt, 0, NNODES * 4, stream);
    hipMemsetAsync(cur, 0, NNODES * 4, stream);

    // ---- weight prep ----
    split_w(stream, 0, tb_w0,   W0h,  W0l,  136, 256, 160, 256);
    split_w(stream, 0, tb_w1,   W1h,  W1l,  256, 256, 256, 256);
    split_w(stream, 0, tb_w2,   W2h,  W2l,  256, 256, 256, 256);
    split_w(stream, 0, env0_w,  We0h, We0l, 256, 320, 256, 384);
    split_w(stream, 0, lat1_w0, WL0h, WL0l, 384, 256, 384, 256);
    split_w(stream, 0, lat1_w1, WL1h, WL1l, 256, 256, 256, 256);
    split_w(stream, 0, env1_w,  We1h, We1l, 256, 192, 256, 256);
    split_w(stream, 0, lin0_sw, S0h,  S0l,  128, 64,  128, 64);
    split_w(stream, 0, lin0_vw, V0h,  V0l,  128, 64,  128, 64);
    split_w(stream, 1, lin1_sw, S1h,  S1l,  128, 128, 128, 128);
    split_w(stream, 1, lin1_vw, V1h,  V1l,  128, 128, 128, 128);
    split_w(stream, 0, fin_w0,  WF0h, WF0l, 384, 256, 384, 256);
    split_w(stream, 0, fin_w1,  WF1h, WF1l, 256, 128, 256, 128);

    prep_edges_k<<<(E_EDGES * 160) / 256, 256, 0, stream>>>(node_attrs, radial, lengths, eidx, X0, cut);

    // ---- counting sort by center ----
    hist_k<<<(E_EDGES + 255) / 256, 256, 0, stream>>>(eidx, cnt);
    scan_k<<<1, 256, 0, stream>>>(cnt, offs);
    scatter_k<<<(E_EDGES + 255) / 256, 256, 0, stream>>>(eidx, offs, cur, perm);

    // ---- stage A: two-body MLP -> latents ----
    mgemm2(stream, 1, X0, 160, 160, nullptr, 0, 0, W0h, W0l, 160, hA, 256, E_EDGES, 256, nullptr, nullptr);
    mgemm2(stream, 1, hA, 256, 256, nullptr, 0, 0, W1h, W1l, 256, hB, 256, E_EDGES, 256, nullptr, nullptr);
    mgemm2(stream, 2, hB, 256, 256, nullptr, 0, 0, W2h, W2l, 256, lat, 256, E_EDGES, 256, cut, nullptr);

    // ---- stage B ----
    mgemm2(stream, 0, lat, 256, 256, nullptr, 0, 0, We0h, We0l, 256, wall, 320, E_EDGES, 320, nullptr, nullptr);
    envsum_k<320><<<NNODES, 64, 0, stream>>>(wall, ang, perm, offs, cnt, envlin0, ns_e, nv_e);
    tp0f_k<<<(E_EDGES * 64) / 256, 256, 0, stream>>>(wall, ang, ns_e, nv_e, eidx, ts, tv);
    {   // lin0 (N=64): 2-wave kernel
        dim3 block(128);
        dim3 g1((E_EDGES + 127) / 128, 1);
        mgemm_k<<<g1, block, 0, stream>>>(ts, 128, 128, S0h, S0l, 128, fs1, 64, E_EDGES);
        dim3 g2((3 * E_EDGES + 127) / 128, 1);
        mgemm_k<<<g2, block, 0, stream>>>(tv, 128, 128, V0h, V0l, 128, fv1, 64, 3 * E_EDGES);
    }

    // ---- latent update MLP + fused residual blend ----
    mgemm2(stream, 1, lat, 256, 256, ts, 128, 128, WL0h, WL0l, 384, hA, 256, E_EDGES, 256, nullptr, nullptr);
    mgemm2(stream, 3, hA, 256, 256, nullptr, 0, 0, WL1h, WL1l, 256, lat, 256, E_EDGES, 256, cut, res_p);

    // ---- stage C ----
    mgemm2(stream, 0, lat, 256, 256, nullptr, 0, 0, We1h, We1l, 256, wall, 192, E_EDGES, 192, nullptr, nullptr);
    envsum_k<192><<<NNODES, 64, 0, stream>>>(wall, ang, perm, offs, cnt, envlin1, ns2_e, nv2_e);
    tp1f_k<<<(E_EDGES * 64) / 256, 256, 0, stream>>>(fs1, fv1, wall, ns2_e, nv2_e, eidx, ts, tv);
    mgemm2(stream, 0, ts, 128, 128, nullptr, 0, 0, S1h, S1l, 128, fs2, 128, E_EDGES, 128, nullptr, nullptr);
    mgemm2(stream, 0, tv, 128, 128, nullptr, 0, 0, V1h, V1l, 128, fv2, 128, 3 * E_EDGES, 128, nullptr, nullptr);

    // ---- final MLP + output ----
    mgemm2(stream, 1, lat, 256, 256, ts, 128, 128, WF0h, WF0l, 384, hA, 256, E_EDGES, 256, nullptr, nullptr);
    mgemm2(stream, 0, hA, 256, 256, nullptr, 0, 0, WF1h, WF1l, 256, hB, 128, E_EDGES, 128, nullptr, nullptr);
    out_k<<<(E_EDGES * 512) / 256, 256, 0, stream>>>(fs2, hB, fv2, (float*)d_out);
}